// Round 4
// baseline (343.140 us; speedup 1.0000x reference)
//
#include <hip/hip_runtime.h>

// B=4, S=2048, D=1024, scale = 1/sqrt(64) = 0.125
// Workspace layout (105 MB):
//   [0,16M)    Xbf  : features bf16              [8192,1024]
//   [16M,24M)  Wcat bf16: Wq|Wk|Wv|Wo            4 x [1024,1024]
//   [24M,40M)  Q bf16 [8192,1024]  -> reused as attn
//   [40M,56M)  K bf16
//   [56M,72M)  Vt bf16 (V transposed)            [4][1024,2048]
//   [72M,104M) P~ bf16 dense [4][2048,2048]
//   [104M,+32K) lsum fp32 [8192]
//
// R10: BK=32 double-buffer. Session A/B series: QKV time tracks resident
// blocks/CU (R0 5blk/90.7us > R3 2blk/98.6 > R2 1blk/108), and R0's stall
// is the per-step vmcnt(0) drain BEFORE compute (syncthreads semantics).
// BK=32 makes dbuf fit in 32 KB -> keeps 5 blocks/CU AND hides staging
// latency behind compute:
//   iter t: stage(t+1 -> buf^1) -> ds_reads+MFMA on buf -> vmcnt(0) ->
//           s_barrier -> buf ^= 1
// Total LDS reads, barrier count, read:MFMA ratio all unchanged vs R0.
// WAR-safe: each wave passes its own vmcnt(0) before the barrier, so at
// release ALL staging writes have landed; buf is overwritten only one
// iteration after its last read, behind the barrier. The asm "memory"
// clobbers order the LDS reads vs the barrier.
// Swizzle (4 quads/row): phys slot p = (l + R + (R>>2)) & 3 -> within each
// 16-lane fq-group slots hit exactly 2x (2-way = free, m136). Staging
// source pre-rotated with the inverse; gload_lds dest stays linear.
//
// MODE 2: fp32 row-major + bias (out-proj)
// MODE 3: fused QKV epilogue (Q->C, K->C2, Vt->C3 transposed-batched)
// MODE 4: bf16 row-major, acc * 1/lsum[row] (PV normalize)
// MODE 5: exp(scale*acc) bf16 + atomic row sums (scores)

using u16 = unsigned short;
typedef __bf16 bf16x8 __attribute__((ext_vector_type(8)));
typedef float f32x4 __attribute__((ext_vector_type(4)));

#define AS1 __attribute__((address_space(1)))
#define AS3 __attribute__((address_space(3)))

__device__ inline u16 f2bf(float f) {
  union { float f; unsigned int u; } c; c.f = f;
  unsigned int u = c.u;
  u += 0x7fffu + ((u >> 16) & 1u);   // round-to-nearest-even
  return (u16)(u >> 16);
}

// one launch: casts features + all 4 weight matrices, and zeroes lsum
__global__ __launch_bounds__(256) void cast_all(
    const float4* __restrict__ feat, const float4* __restrict__ wq,
    const float4* __restrict__ wk, const float4* __restrict__ wv,
    const float4* __restrict__ wo, ushort4* __restrict__ xbf,
    ushort4* __restrict__ wcat, float* __restrict__ lsum) {
  const int b = blockIdx.x, tx = threadIdx.x;
  if (b >= 12288) {                      // 32 trailing blocks zero lsum[8192]
    lsum[(b - 12288) * 256 + tx] = 0.f;
    return;
  }
  const float4* src; ushort4* dst; int idx;
  if (b < 8192) { src = feat; dst = xbf; idx = b * 256 + tx; }
  else {
    const int w = (b - 8192) >> 10, loc = ((b - 8192) & 1023) * 256 + tx;
    src = (w == 0) ? wq : (w == 1) ? wk : (w == 2) ? wv : wo;
    dst = wcat + w * 262144; idx = loc;
  }
  float4 v = src[idx];
  ushort4 o;
  o.x = f2bf(v.x); o.y = f2bf(v.y); o.z = f2bf(v.z); o.w = f2bf(v.w);
  dst[idx] = o;
}

template <int MODE>
__global__ __launch_bounds__(256) void gemm_bt(
    const u16* __restrict__ A, const u16* __restrict__ Bm, void* __restrict__ C,
    void* __restrict__ C2, void* __restrict__ C3,
    const float* __restrict__ bias, const float* __restrict__ bias2,
    const float* __restrict__ bias3, float* __restrict__ lsum,
    int M, int N, int K, int lda, int ldc,
    float scale,
    long long sA, long long sB, long long sC)
{
  __shared__ u16 As[2 * 128 * 32];   // [buf][row][32]
  __shared__ u16 Bs[2 * 128 * 32];
  const int tx = threadIdx.x;
  const int wave = tx >> 6, lane = tx & 63;
  const int wm = (wave >> 1) * 64, wn = (wave & 1) * 64;
  const int m0 = blockIdx.y * 128, n0 = blockIdx.x * 128;
  const u16* Ab = A + blockIdx.z * sA + (long long)m0 * lda;
  const u16* Bb = Bm + blockIdx.z * sB + (long long)n0 * K;

  f32x4 acc[4][4] = {};

  // staging: issue t in {0,1}, chunk c = t*256 + wave*64 + lane covers 16B
  // quad p = c&3 of row r = c>>2. Phys quad p holds logical quad
  // l = (p - r - (r>>2)) & 3  (inverse of the read rotation).
  int rT[2], lT[2];
#pragma unroll
  for (int t = 0; t < 2; ++t) {
    rT[t] = t * 64 + wave * 16 + (lane >> 2);
    lT[t] = (((lane & 3) - rT[t] - (rT[t] >> 2)) & 3) << 3;  // elem offset
  }
  // wave-uniform LDS dest base (elements) for issue t (HW adds lane*16B)
  const int ldsT[2] = {wave * 512, 2048 + wave * 512};

  const int fr = lane & 15, fq = lane >> 4;

  auto stage = [&](int k0, int buf) {
#pragma unroll
    for (int t = 0; t < 2; ++t) {
      __builtin_amdgcn_global_load_lds(
          (const AS1 void*)(Ab + (long long)rT[t] * lda + k0 + lT[t]),
          (AS3 void*)(As + buf * 4096 + ldsT[t]), 16, 0, 0);
      __builtin_amdgcn_global_load_lds(
          (const AS1 void*)(Bb + (long long)rT[t] * K + k0 + lT[t]),
          (AS3 void*)(Bs + buf * 4096 + ldsT[t]), 16, 0, 0);
    }
  };

  // prologue: tile 0 into buf 0, drain, fence
  stage(0, 0);
  asm volatile("s_waitcnt vmcnt(0)" ::: "memory");
  __builtin_amdgcn_s_barrier();

  int cur = 0;
  for (int k0 = 0; k0 < K; k0 += 32) {
    if (k0 + 32 < K) stage(k0 + 32, cur ^ 1);   // issue next-tile loads first

    const u16* Ac = As + cur * 4096;
    const u16* Bc = Bs + cur * 4096;
    bf16x8 af[4], bfv[4];
#pragma unroll
    for (int i = 0; i < 4; ++i) {
      const int Ra = wm + i * 16 + fr;
      const int Rb = wn + i * 16 + fr;
      af[i]  = *(const bf16x8*)(Ac + Ra * 32 + (((fq + Ra + (Ra >> 2)) & 3) << 3));
      bfv[i] = *(const bf16x8*)(Bc + Rb * 32 + (((fq + Rb + (Rb >> 2)) & 3) << 3));
    }
#pragma unroll
    for (int i = 0; i < 4; ++i)
#pragma unroll
      for (int j = 0; j < 4; ++j)
        acc[i][j] = __builtin_amdgcn_mfma_f32_16x16x32_bf16(af[i], bfv[j], acc[i][j], 0, 0, 0);

    // next tile's staging loads have landed (each wave waits its own; the
    // barrier joins all waves, so buf^1 is fully populated after release).
    asm volatile("s_waitcnt vmcnt(0)" ::: "memory");
    __builtin_amdgcn_s_barrier();
    cur ^= 1;
  }

  // epilogue: C/D layout col=lane&15, row=(lane>>4)*4+reg
  const int col = lane & 15, rq = (lane >> 4) << 2;
  const long long zC = (long long)blockIdx.z * sC;

  if constexpr (MODE == 5) {
    // exp + bf16 store + per-row sum (reduce over 16 col-lanes, atomicAdd)
    float rsum[4][4] = {};   // [i][r]
#pragma unroll
    for (int i = 0; i < 4; ++i) {
#pragma unroll
      for (int j = 0; j < 4; ++j) {
        const int gn = n0 + wn + j * 16 + col;
#pragma unroll
        for (int r = 0; r < 4; ++r) {
          const int gm = m0 + wm + i * 16 + rq + r;
          const float e = __expf(acc[i][j][r] * scale);
          ((u16*)C)[zC + (long long)gm * ldc + gn] = f2bf(e);
          rsum[i][r] += e;
        }
      }
    }
#pragma unroll
    for (int i = 0; i < 4; ++i) {
#pragma unroll
      for (int r = 0; r < 4; ++r) {
        float s = rsum[i][r];
        s += __shfl_xor(s, 1); s += __shfl_xor(s, 2);
        s += __shfl_xor(s, 4); s += __shfl_xor(s, 8);
        if (col == 0)
          atomicAdd(&lsum[(long long)blockIdx.z * 2048 + m0 + wm + i * 16 + rq + r], s);
      }
    }
  } else if constexpr (MODE == 4) {
    float inv[4][4];
#pragma unroll
    for (int i = 0; i < 4; ++i)
#pragma unroll
      for (int r = 0; r < 4; ++r)
        inv[i][r] = 1.0f / lsum[(long long)blockIdx.z * 2048 + m0 + wm + i * 16 + rq + r];
#pragma unroll
    for (int i = 0; i < 4; ++i)
#pragma unroll
      for (int j = 0; j < 4; ++j) {
        const int gn = n0 + wn + j * 16 + col;
#pragma unroll
        for (int r = 0; r < 4; ++r) {
          const int gm = m0 + wm + i * 16 + rq + r;
          ((u16*)C)[zC + (long long)gm * ldc + gn] = f2bf(acc[i][j][r] * inv[i][r]);
        }
      }
  } else if constexpr (MODE == 3) {
    const int sect = n0 >> 10;  // 0=Q 1=K 2=V (n0 128-aligned, uniform)
#pragma unroll
    for (int i = 0; i < 4; ++i) {
#pragma unroll
      for (int j = 0; j < 4; ++j) {
        const int gn = n0 + wn + j * 16 + col;
        const int nb = gn & 1023;
        const float bv = (sect == 0) ? bias[nb] : (sect == 1) ? bias2[nb] : bias3[nb];
#pragma unroll
        for (int r = 0; r < 4; ++r) {
          const int gm = m0 + wm + i * 16 + rq + r;
          const float v = acc[i][j][r] + bv;
          if (sect == 0) {
            ((u16*)C)[(long long)gm * 1024 + nb] = f2bf(v);
          } else if (sect == 1) {
            ((u16*)C2)[(long long)gm * 1024 + nb] = f2bf(v);
          } else {
            const int bb = gm >> 11, t = gm & 2047;
            ((u16*)C3)[((long long)bb << 21) + (long long)nb * 2048 + t] = f2bf(v);
          }
        }
      }
    }
  } else {  // MODE == 2: fp32 row-major + bias
#pragma unroll
    for (int i = 0; i < 4; ++i) {
#pragma unroll
      for (int j = 0; j < 4; ++j) {
        const int gn = n0 + wn + j * 16 + col;
        const float bv = bias[gn];
#pragma unroll
        for (int r = 0; r < 4; ++r) {
          const int gm = m0 + wm + i * 16 + rq + r;
          ((float*)C)[zC + (long long)gm * ldc + gn] = acc[i][j][r] + bv;
        }
      }
    }
  }
}

extern "C" void kernel_launch(void* const* d_in, const int* in_sizes, int n_in,
                              void* d_out, int out_size, void* d_ws, size_t ws_size,
                              hipStream_t stream) {
  (void)in_sizes; (void)n_in; (void)out_size; (void)ws_size;
  const float* feat = (const float*)d_in[0];
  const float* Wq = (const float*)d_in[1];
  const float* bq = (const float*)d_in[2];
  const float* Wk = (const float*)d_in[3];
  const float* bk = (const float*)d_in[4];
  const float* Wv = (const float*)d_in[5];
  const float* bv = (const float*)d_in[6];
  const float* Wo = (const float*)d_in[7];
  const float* bo = (const float*)d_in[8];
  float* out = (float*)d_out;

  char* ws = (char*)d_ws;
  const unsigned long long MB = 1024ull * 1024ull;
  u16* Xbf  = (u16*)(ws);
  u16* Wcat = (u16*)(ws + 16 * MB);           // Wq|Wk|Wv|Wo bf16
  u16* Wob  = Wcat + 3ll * 1024 * 1024;
  u16* Q    = (u16*)(ws + 24 * MB);           // reused as attn later
  u16* Kbuf = (u16*)(ws + 40 * MB);
  u16* Vt   = (u16*)(ws + 56 * MB);
  u16* P    = (u16*)(ws + 72 * MB);           // dense bf16 [4][2048,2048]
  float* lsum = (float*)(ws + 104 * MB);      // [8192]
  u16* attn = Q;

  dim3 blk(256);

  // casts (features + 4 weights) + lsum zeroing in one launch
  cast_all<<<12320, blk, 0, stream>>>((const float4*)feat, (const float4*)Wq,
                                      (const float4*)Wk, (const float4*)Wv,
                                      (const float4*)Wo, (ushort4*)Xbf,
                                      (ushort4*)Wcat, lsum);

  // fused QKV projection: N=3072 over Wq|Wk|Wv; V written transposed per batch
  gemm_bt<3><<<dim3(24, 64, 1), blk, 0, stream>>>(
      Xbf, Wcat, Q, Kbuf, Vt, bq, bk, bv, nullptr,
      8192, 3072, 1024, 1024, 0, 1.f, 0, 0, 0);

  // P~ = exp(Q K^T * 0.125) bf16 + row sums -> lsum (all 4 batches)
  gemm_bt<5><<<dim3(16, 16, 4), blk, 0, stream>>>(
      Q, Kbuf, P, nullptr, nullptr, nullptr, nullptr, nullptr, lsum,
      2048, 2048, 1024, 1024, 2048, 0.125f,
      2048ll * 1024, 2048ll * 1024, 2048ll * 2048);

  // attn = (P~ @ V) / lsum  (batched; B operand is Vt)
  gemm_bt<4><<<dim3(8, 16, 4), blk, 0, stream>>>(
      P, Vt, attn, nullptr, nullptr, nullptr, nullptr, nullptr, lsum,
      2048, 1024, 2048, 2048, 1024, 1.f,
      2048ll * 2048, 1024ll * 2048, 2048ll * 1024);

  // out = attn @ Wo^T + bo  (fp32 output)
  gemm_bt<2><<<dim3(8, 64, 1), blk, 0, stream>>>(
      attn, Wob, out, nullptr, nullptr, bo, nullptr, nullptr, nullptr,
      8192, 1024, 1024, 1024, 1024, 1.f, 0, 0, 0);
}

// Round 6
// 309.727 us; speedup vs baseline: 1.1079x; 1.1079x over previous
//
#include <hip/hip_runtime.h>

// B=4, S=2048, D=1024, scale = 1/sqrt(64) = 0.125
// Workspace layout (105 MB):
//   [0,16M)    Xbf  : features bf16              [8192,1024]
//   [16M,24M)  Wcat bf16: Wq|Wk|Wv|Wo            4 x [1024,1024]
//   [24M,40M)  Q bf16 [8192,1024]  -> reused as attn
//   [40M,56M)  K bf16
//   [56M,72M)  Vt bf16 (V transposed)            [4][1024,2048]
//   [72M,104M) P~ bf16 dense [4][2048,2048]
//   [104M,+32K) lsum fp32 [8192]
//
// R12 = R11 resubmitted (R5 bench was an infra failure, no signal).
// R11 = R0 (measured 90.7us QKV / 307.9us total, the session best) + ONE
// change: XCD-aware bijective block swizzle (catalog T1, m157/m204).
// Evidence: QKV FETCH_SIZE = 72 MB vs 22 MB ideal (3.3x overfetch). Default
// round-robin block->XCD placement gives each XCD blocks {i, i+8, ...}:
// x cycles mod 24 while y advances every 3 -> every XCD streams ~all 16 MB
// of A through its 4 MB L2, and each K-step's staging drain waits on L3/HBM
// latency (~400-900 cyc) instead of L2 hits (~200). Swizzle w=(f&7)*(n/8)+
// f/8 gives each XCD a contiguous run of flat ids = 8 contiguous A-row-
// panels x all x -> A L2-resident after the first column sweep. All four
// grids (1536,1024,512,512) are %8==0 -> bijective. Applied uniformly; no
// other change vs R0. R1-R4 lesson: pipeline re-plumbing at this tile size
// is neutral-to-negative (R3 dbuf: -occupancy; R4 BK32: bank conflicts).
//
// MODE 2: fp32 row-major + bias (out-proj)
// MODE 3: fused QKV epilogue (Q->C, K->C2, Vt->C3 transposed-batched)
// MODE 4: bf16 row-major, acc * 1/lsum[row] (PV normalize)
// MODE 5: exp(scale*acc) bf16 + atomic row sums (scores)

using u16 = unsigned short;
typedef __bf16 bf16x8 __attribute__((ext_vector_type(8)));
typedef float f32x4 __attribute__((ext_vector_type(4)));

#define AS1 __attribute__((address_space(1)))
#define AS3 __attribute__((address_space(3)))

__device__ inline u16 f2bf(float f) {
  union { float f; unsigned int u; } c; c.f = f;
  unsigned int u = c.u;
  u += 0x7fffu + ((u >> 16) & 1u);   // round-to-nearest-even
  return (u16)(u >> 16);
}

// one launch: casts features + all 4 weight matrices, and zeroes lsum
__global__ __launch_bounds__(256) void cast_all(
    const float4* __restrict__ feat, const float4* __restrict__ wq,
    const float4* __restrict__ wk, const float4* __restrict__ wv,
    const float4* __restrict__ wo, ushort4* __restrict__ xbf,
    ushort4* __restrict__ wcat, float* __restrict__ lsum) {
  const int b = blockIdx.x, tx = threadIdx.x;
  if (b >= 12288) {                      // 32 trailing blocks zero lsum[8192]
    lsum[(b - 12288) * 256 + tx] = 0.f;
    return;
  }
  const float4* src; ushort4* dst; int idx;
  if (b < 8192) { src = feat; dst = xbf; idx = b * 256 + tx; }
  else {
    const int w = (b - 8192) >> 10, loc = ((b - 8192) & 1023) * 256 + tx;
    src = (w == 0) ? wq : (w == 1) ? wk : (w == 2) ? wv : wo;
    dst = wcat + w * 262144; idx = loc;
  }
  float4 v = src[idx];
  ushort4 o;
  o.x = f2bf(v.x); o.y = f2bf(v.y); o.z = f2bf(v.z); o.w = f2bf(v.w);
  dst[idx] = o;
}

template <int MODE>
__global__ __launch_bounds__(256) void gemm_bt(
    const u16* __restrict__ A, const u16* __restrict__ Bm, void* __restrict__ C,
    void* __restrict__ C2, void* __restrict__ C3,
    const float* __restrict__ bias, const float* __restrict__ bias2,
    const float* __restrict__ bias3, float* __restrict__ lsum,
    int M, int N, int K, int lda, int ldc,
    float scale,
    long long sA, long long sB, long long sC)
{
  __shared__ u16 As[128 * 64];
  __shared__ u16 Bs[128 * 64];
  const int tx = threadIdx.x;
  const int wave = tx >> 6, lane = tx & 63;
  const int wm = (wave >> 1) * 64, wn = (wave & 1) * 64;

  // XCD-aware bijective block swizzle (T1): consecutive work ids (x-fastest,
  // sharing an A-row-panel) land on the SAME XCD -> A panels L2-resident.
  // All grids here are divisible by 8, so this is a bijection.
  const int nwg = gridDim.x * gridDim.y * gridDim.z;
  const int f = blockIdx.x + gridDim.x * (blockIdx.y + gridDim.y * blockIdx.z);
  const int w = (f & 7) * (nwg >> 3) + (f >> 3);
  const int bx = w % gridDim.x;
  const int rem = w / gridDim.x;
  const int by = rem % gridDim.y;
  const int bz = rem / gridDim.y;

  const int m0 = by * 128, n0 = bx * 128;
  const u16* Ab = A + bz * sA + (long long)m0 * lda;
  const u16* Bb = Bm + bz * sB + (long long)n0 * K;

  f32x4 acc[4][4] = {};

  // staging: issue t in 0..3, physical chunk c = t*256 + wave*64 + lane
  // r = c>>3 = t*32 + wave*8 + (lane>>3); slot p = lane&7; quad q=(p-r)&7
  int rT[4], qT[4];
#pragma unroll
  for (int t = 0; t < 4; ++t) {
    rT[t] = t * 32 + wave * 8 + (lane >> 3);
    qT[t] = (((lane & 7) - rT[t]) & 7) << 3;   // element offset of 8-elem quad
  }
  // wave-uniform LDS dest base for issue t (HW adds lane*16B)
  const int ldsT[4] = {wave * 512, 2048 + wave * 512, 4096 + wave * 512,
                       6144 + wave * 512};

  const int fr = lane & 15, fq = lane >> 4;

  for (int k0 = 0; k0 < K; k0 += 64) {
#pragma unroll
    for (int t = 0; t < 4; ++t) {
      __builtin_amdgcn_global_load_lds(
          (const AS1 void*)(Ab + (long long)rT[t] * lda + k0 + qT[t]),
          (AS3 void*)(As + ldsT[t]), 16, 0, 0);
      __builtin_amdgcn_global_load_lds(
          (const AS1 void*)(Bb + (long long)rT[t] * K + k0 + qT[t]),
          (AS3 void*)(Bs + ldsT[t]), 16, 0, 0);
    }
    __syncthreads();

#pragma unroll
    for (int s = 0; s < 2; ++s) {
      bf16x8 af[4], bfv[4];
#pragma unroll
      for (int i = 0; i < 4; ++i) {
        const int Ra = wm + i * 16 + fr;
        const int Rb = wn + i * 16 + fr;
        af[i]  = *(const bf16x8*)(As + Ra * 64 + (((s * 4 + fq + Ra) & 7) << 3));
        bfv[i] = *(const bf16x8*)(Bs + Rb * 64 + (((s * 4 + fq + Rb) & 7) << 3));
      }
#pragma unroll
      for (int i = 0; i < 4; ++i)
#pragma unroll
        for (int j = 0; j < 4; ++j)
          acc[i][j] = __builtin_amdgcn_mfma_f32_16x16x32_bf16(af[i], bfv[j], acc[i][j], 0, 0, 0);
    }
    __syncthreads();
  }

  // epilogue: C/D layout col=lane&15, row=(lane>>4)*4+reg
  const int col = lane & 15, rq = (lane >> 4) << 2;
  const long long zC = (long long)bz * sC;

  if constexpr (MODE == 5) {
    // exp + bf16 store + per-row sum (reduce over 16 col-lanes, atomicAdd)
    float rsum[4][4] = {};   // [i][r]
#pragma unroll
    for (int i = 0; i < 4; ++i) {
#pragma unroll
      for (int j = 0; j < 4; ++j) {
        const int gn = n0 + wn + j * 16 + col;
#pragma unroll
        for (int r = 0; r < 4; ++r) {
          const int gm = m0 + wm + i * 16 + rq + r;
          const float e = __expf(acc[i][j][r] * scale);
          ((u16*)C)[zC + (long long)gm * ldc + gn] = f2bf(e);
          rsum[i][r] += e;
        }
      }
    }
#pragma unroll
    for (int i = 0; i < 4; ++i) {
#pragma unroll
      for (int r = 0; r < 4; ++r) {
        float s = rsum[i][r];
        s += __shfl_xor(s, 1); s += __shfl_xor(s, 2);
        s += __shfl_xor(s, 4); s += __shfl_xor(s, 8);
        if (col == 0)
          atomicAdd(&lsum[(long long)bz * 2048 + m0 + wm + i * 16 + rq + r], s);
      }
    }
  } else if constexpr (MODE == 4) {
    float inv[4][4];
#pragma unroll
    for (int i = 0; i < 4; ++i)
#pragma unroll
      for (int r = 0; r < 4; ++r)
        inv[i][r] = 1.0f / lsum[(long long)bz * 2048 + m0 + wm + i * 16 + rq + r];
#pragma unroll
    for (int i = 0; i < 4; ++i)
#pragma unroll
      for (int j = 0; j < 4; ++j) {
        const int gn = n0 + wn + j * 16 + col;
#pragma unroll
        for (int r = 0; r < 4; ++r) {
          const int gm = m0 + wm + i * 16 + rq + r;
          ((u16*)C)[zC + (long long)gm * ldc + gn] = f2bf(acc[i][j][r] * inv[i][r]);
        }
      }
  } else if constexpr (MODE == 3) {
    const int sect = n0 >> 10;  // 0=Q 1=K 2=V (n0 128-aligned, uniform)
#pragma unroll
    for (int i = 0; i < 4; ++i) {
#pragma unroll
      for (int j = 0; j < 4; ++j) {
        const int gn = n0 + wn + j * 16 + col;
        const int nb = gn & 1023;
        const float bv = (sect == 0) ? bias[nb] : (sect == 1) ? bias2[nb] : bias3[nb];
#pragma unroll
        for (int r = 0; r < 4; ++r) {
          const int gm = m0 + wm + i * 16 + rq + r;
          const float v = acc[i][j][r] + bv;
          if (sect == 0) {
            ((u16*)C)[(long long)gm * 1024 + nb] = f2bf(v);
          } else if (sect == 1) {
            ((u16*)C2)[(long long)gm * 1024 + nb] = f2bf(v);
          } else {
            const int bb = gm >> 11, t = gm & 2047;
            ((u16*)C3)[((long long)bb << 21) + (long long)nb * 2048 + t] = f2bf(v);
          }
        }
      }
    }
  } else {  // MODE == 2: fp32 row-major + bias
#pragma unroll
    for (int i = 0; i < 4; ++i) {
#pragma unroll
      for (int j = 0; j < 4; ++j) {
        const int gn = n0 + wn + j * 16 + col;
        const float bv = bias[gn];
#pragma unroll
        for (int r = 0; r < 4; ++r) {
          const int gm = m0 + wm + i * 16 + rq + r;
          ((float*)C)[zC + (long long)gm * ldc + gn] = acc[i][j][r] + bv;
        }
      }
    }
  }
}

extern "C" void kernel_launch(void* const* d_in, const int* in_sizes, int n_in,
                              void* d_out, int out_size, void* d_ws, size_t ws_size,
                              hipStream_t stream) {
  (void)in_sizes; (void)n_in; (void)out_size; (void)ws_size;
  const float* feat = (const float*)d_in[0];
  const float* Wq = (const float*)d_in[1];
  const float* bq = (const float*)d_in[2];
  const float* Wk = (const float*)d_in[3];
  const float* bk = (const float*)d_in[4];
  const float* Wv = (const float*)d_in[5];
  const float* bv = (const float*)d_in[6];
  const float* Wo = (const float*)d_in[7];
  const float* bo = (const float*)d_in[8];
  float* out = (float*)d_out;

  char* ws = (char*)d_ws;
  const unsigned long long MB = 1024ull * 1024ull;
  u16* Xbf  = (u16*)(ws);
  u16* Wcat = (u16*)(ws + 16 * MB);           // Wq|Wk|Wv|Wo bf16
  u16* Wob  = Wcat + 3ll * 1024 * 1024;
  u16* Q    = (u16*)(ws + 24 * MB);           // reused as attn later
  u16* Kbuf = (u16*)(ws + 40 * MB);
  u16* Vt   = (u16*)(ws + 56 * MB);
  u16* P    = (u16*)(ws + 72 * MB);           // dense bf16 [4][2048,2048]
  float* lsum = (float*)(ws + 104 * MB);      // [8192]
  u16* attn = Q;

  dim3 blk(256);

  // casts (features + 4 weights) + lsum zeroing in one launch
  cast_all<<<12320, blk, 0, stream>>>((const float4*)feat, (const float4*)Wq,
                                      (const float4*)Wk, (const float4*)Wv,
                                      (const float4*)Wo, (ushort4*)Xbf,
                                      (ushort4*)Wcat, lsum);

  // fused QKV projection: N=3072 over Wq|Wk|Wv; V written transposed per batch
  gemm_bt<3><<<dim3(24, 64, 1), blk, 0, stream>>>(
      Xbf, Wcat, Q, Kbuf, Vt, bq, bk, bv, nullptr,
      8192, 3072, 1024, 1024, 0, 1.f, 0, 0, 0);

  // P~ = exp(Q K^T * 0.125) bf16 + row sums -> lsum (all 4 batches)
  gemm_bt<5><<<dim3(16, 16, 4), blk, 0, stream>>>(
      Q, Kbuf, P, nullptr, nullptr, nullptr, nullptr, nullptr, lsum,
      2048, 2048, 1024, 1024, 2048, 0.125f,
      2048ll * 1024, 2048ll * 1024, 2048ll * 2048);

  // attn = (P~ @ V) / lsum  (batched; B operand is Vt)
  gemm_bt<4><<<dim3(8, 16, 4), blk, 0, stream>>>(
      P, Vt, attn, nullptr, nullptr, nullptr, nullptr, nullptr, lsum,
      2048, 1024, 2048, 2048, 1024, 1.f,
      2048ll * 2048, 1024ll * 2048, 2048ll * 1024);

  // out = attn @ Wo^T + bo  (fp32 output)
  gemm_bt<2><<<dim3(8, 64, 1), blk, 0, stream>>>(
      attn, Wob, out, nullptr, nullptr, bo, nullptr, nullptr, nullptr,
      8192, 1024, 1024, 1024, 1024, 1.f, 0, 0, 0);
}